// Round 1
// baseline (227.077 us; speedup 1.0000x reference)
//
#include <hip/hip_runtime.h>
#include <stdint.h>

typedef uint16_t u16;
typedef uint32_t u32;

#define NS 4096
#define NTOT 8192
#define DIM 512
#define LOG2E 1.4426950408889634

typedef __attribute__((ext_vector_type(8))) short bf16x8;
typedef __attribute__((ext_vector_type(4))) float f32x4;

__device__ inline u16 f2bf(float f) {
    u32 u = __float_as_uint(f);
    u32 r = (u + 0x7fffu + ((u >> 16) & 1u)) >> 16;
    return (u16)r;
}

__device__ inline void load_lds16(const void* g, void* l) {
    __builtin_amdgcn_global_load_lds((__attribute__((address_space(1))) void*)g,
                                     (__attribute__((address_space(3))) void*)l,
                                     16, 0, 0);
}

// k1: per-row sumsq (fp32), bf16 conversion of total, per-block column partial sums.
// grid 512 blocks x 256 thr; block b handles rows [16b, 16b+16); wave w rows w*4..w*4+3.
__global__ __launch_bounds__(256) void k_prep(const float* __restrict__ src,
                                              const float* __restrict__ tgt,
                                              u16* __restrict__ Tb,
                                              float* __restrict__ sq,
                                              float* __restrict__ cp) {
    __shared__ float cs_l[4][DIM];
    const int b = blockIdx.x;
    const int tid = threadIdx.x;
    const int w = tid >> 6, lane = tid & 63;

    float cs[8];
#pragma unroll
    for (int e = 0; e < 8; ++e) cs[e] = 0.f;

#pragma unroll
    for (int j = 0; j < 4; ++j) {
        const int r = b * 16 + w * 4 + j;
        const float* rowp = (r < NS) ? (src + (size_t)r * DIM)
                                     : (tgt + (size_t)(r - NS) * DIM);
        float4 v0 = *(const float4*)(rowp + lane * 8);
        float4 v1 = *(const float4*)(rowp + lane * 8 + 4);
        float vx[8] = {v0.x, v0.y, v0.z, v0.w, v1.x, v1.y, v1.z, v1.w};
        float ss = 0.f;
#pragma unroll
        for (int e = 0; e < 8; ++e) { ss += vx[e] * vx[e]; cs[e] += vx[e]; }
        u32 pk[4];
#pragma unroll
        for (int e = 0; e < 4; ++e)
            pk[e] = (u32)f2bf(vx[2 * e]) | ((u32)f2bf(vx[2 * e + 1]) << 16);
        *(uint4*)(Tb + (size_t)r * DIM + lane * 8) = make_uint4(pk[0], pk[1], pk[2], pk[3]);
#pragma unroll
        for (int off = 32; off; off >>= 1) ss += __shfl_down(ss, off);
        if (lane == 0) sq[r] = ss;
    }
#pragma unroll
    for (int e = 0; e < 8; ++e) cs_l[w][lane * 8 + e] = cs[e];
    __syncthreads();
    float a0 = cs_l[0][tid] + cs_l[1][tid] + cs_l[2][tid] + cs_l[3][tid];
    float a1 = cs_l[0][tid + 256] + cs_l[1][tid + 256] + cs_l[2][tid + 256] + cs_l[3][tid + 256];
    cp[(size_t)b * DIM + tid] = a0;
    cp[(size_t)b * DIM + tid + 256] = a1;
}

// k2: bandwidth via identity sum(l2) = 2*N*sum(sq) - 2*||colsum||^2; writes 5 exp2 scales.
__global__ __launch_bounds__(256) void k_band(const float* __restrict__ sq,
                                              const float* __restrict__ cp,
                                              float* __restrict__ scales) {
    __shared__ double red[4];
    const int tid = threadIdx.x;
    const int w = tid >> 6, lane = tid & 63;

    double ssq = 0.0;
    for (int i = tid; i < NTOT; i += 256) ssq += (double)sq[i];

    double s2 = 0.0;
    for (int c = tid; c < DIM; c += 256) {
        double sc = 0.0;
        for (int b = 0; b < 512; ++b) sc += (double)cp[(size_t)b * DIM + c];
        s2 += sc * sc;
    }

    auto blkreduce = [&](double v) -> double {
#pragma unroll
        for (int off = 32; off; off >>= 1) v += __shfl_down(v, off);
        __syncthreads();
        if (lane == 0) red[w] = v;
        __syncthreads();
        return red[0] + red[1] + red[2] + red[3];
    };

    double sumsq = blkreduce(ssq);
    double s2t = blkreduce(s2);

    if (tid < 5) {
        const double nn = (double)NTOT;
        double bw = (2.0 * nn * sumsq - 2.0 * s2t) / (nn * nn - nn);
        const double fac[5] = {0.25, 0.5, 1.0, 2.0, 4.0};
        scales[tid] = (float)(-LOG2E / (bw * fac[tid] + 1e-8));
    }
}

// k3: main pass. 128x128 tile per block (4 waves, each 64x64 via 4x4 mfma_f32_16x16x32_bf16),
// global_load_lds(16B) staging, epilogue computes l2 -> 5x exp2 -> weighted double sum.
__global__ __launch_bounds__(256) void k_mmd(const u16* __restrict__ Tb,
                                             const float* __restrict__ sq,
                                             const float* __restrict__ scales,
                                             double* __restrict__ partials) {
    __shared__ __align__(16) u16 As[128 * 32];
    __shared__ __align__(16) u16 Bs[128 * 32];
    __shared__ double red[4];

    const int bj = blockIdx.x, bi = blockIdx.y;
    const int tid = threadIdx.x;
    const int wid = tid >> 6, lane = tid & 63;
    const int wr = wid >> 1, wc = wid & 1;

    f32x4 acc[4][4];
#pragma unroll
    for (int m = 0; m < 4; ++m)
#pragma unroll
        for (int n = 0; n < 4; ++n) acc[m][n] = (f32x4){0.f, 0.f, 0.f, 0.f};

    const int rowA0 = bi * 128, rowB0 = bj * 128;
    const int srow = lane >> 2;          // 0..15 within 16-row chunk
    const int scol = (lane & 3) * 8;     // bf16 octet within BK=32
    const int fr = lane & 15, fq = lane >> 4;

    for (int kt = 0; kt < DIM / 32; ++kt) {
        const int k0 = kt * 32;
#pragma unroll
        for (int q = 0; q < 2; ++q) {
            const int c = wid * 2 + q;   // chunk 0..7, wave-uniform
            const u16* ga = Tb + (size_t)(rowA0 + c * 16 + srow) * DIM + k0 + scol;
            const u16* gb = Tb + (size_t)(rowB0 + c * 16 + srow) * DIM + k0 + scol;
            load_lds16(ga, (char*)As + c * 1024);
            load_lds16(gb, (char*)Bs + c * 1024);
        }
        __syncthreads();   // drains vmcnt before barrier (compiler-inserted)

        bf16x8 af[4], bf[4];
#pragma unroll
        for (int m = 0; m < 4; ++m)
            af[m] = *(const bf16x8*)(As + (wr * 64 + m * 16 + fr) * 32 + fq * 8);
#pragma unroll
        for (int n = 0; n < 4; ++n)
            bf[n] = *(const bf16x8*)(Bs + (wc * 64 + n * 16 + fr) * 32 + fq * 8);
#pragma unroll
        for (int m = 0; m < 4; ++m)
#pragma unroll
            for (int n = 0; n < 4; ++n)
                acc[m][n] = __builtin_amdgcn_mfma_f32_16x16x32_bf16(af[m], bf[n], acc[m][n], 0, 0, 0);
        __syncthreads();
    }

    // epilogue
    const float c0 = scales[0], c1 = scales[1], c2 = scales[2], c3 = scales[3], c4 = scales[4];
    float sqc[4];
#pragma unroll
    for (int n = 0; n < 4; ++n) sqc[n] = sq[rowB0 + wc * 64 + n * 16 + fr];

    double lacc = 0.0;
#pragma unroll
    for (int m = 0; m < 4; ++m) {
        float4 s4 = *(const float4*)(sq + rowA0 + wr * 64 + m * 16 + fq * 4);
        float sqr[4] = {s4.x, s4.y, s4.z, s4.w};
#pragma unroll
        for (int n = 0; n < 4; ++n) {
#pragma unroll
            for (int r = 0; r < 4; ++r) {
                float g = acc[m][n][r];
                float l2 = fmaxf(sqr[r] + sqc[n] - 2.0f * g, 0.0f);
                float ks = exp2f(c0 * l2) + exp2f(c1 * l2) + exp2f(c2 * l2)
                         + exp2f(c3 * l2) + exp2f(c4 * l2);
                lacc += (double)ks;
            }
        }
    }

    const double wsign = ((bi < 32) == (bj < 32)) ? 1.0 : -1.0;
#pragma unroll
    for (int off = 32; off; off >>= 1) lacc += __shfl_down(lacc, off);
    if (lane == 0) red[wid] = lacc;
    __syncthreads();
    if (tid == 0)
        partials[(size_t)bi * 64 + bj] = (red[0] + red[1] + red[2] + red[3]) * wsign;
}

// k4: final reduce of 4096 block partials -> scalar
__global__ __launch_bounds__(256) void k_final(const double* __restrict__ partials,
                                               float* __restrict__ out) {
    __shared__ double red[4];
    const int tid = threadIdx.x;
    const int w = tid >> 6, lane = tid & 63;
    double v = 0.0;
    for (int i = tid; i < 4096; i += 256) v += partials[i];
#pragma unroll
    for (int off = 32; off; off >>= 1) v += __shfl_down(v, off);
    if (lane == 0) red[w] = v;
    __syncthreads();
    if (tid == 0)
        out[0] = (float)((red[0] + red[1] + red[2] + red[3]) / ((double)NS * (double)NS));
}

extern "C" void kernel_launch(void* const* d_in, const int* in_sizes, int n_in,
                              void* d_out, int out_size, void* d_ws, size_t ws_size,
                              hipStream_t stream) {
    const float* src = (const float*)d_in[0];
    const float* tgt = (const float*)d_in[1];
    char* ws = (char*)d_ws;

    u16* Tb       = (u16*)ws;                                  // 8 MiB
    float* sq     = (float*)(ws + 8u * 1024 * 1024);           // 32 KiB
    float* cp     = (float*)(ws + 8u * 1024 * 1024 + 32 * 1024);          // 1 MiB
    float* scales = (float*)(ws + 8u * 1024 * 1024 + 32 * 1024 + 1024 * 1024); // 32 B
    double* parts = (double*)(ws + 8u * 1024 * 1024 + 32 * 1024 + 1024 * 1024 + 256); // 32 KiB

    k_prep<<<512, 256, 0, stream>>>(src, tgt, Tb, sq, cp);
    k_band<<<1, 256, 0, stream>>>(sq, cp, scales);
    k_mmd<<<dim3(64, 64), 256, 0, stream>>>(Tb, sq, scales, parts);
    k_final<<<1, 256, 0, stream>>>(parts, (float*)d_out);
}

// Round 3
// 206.484 us; speedup vs baseline: 1.0997x; 1.0997x over previous
//
#include <hip/hip_runtime.h>
#include <stdint.h>

typedef uint16_t u16;
typedef uint32_t u32;

#define NS 4096
#define NTOT 8192
#define DIM 512
#define LOG2E 1.4426950408889634

typedef __attribute__((ext_vector_type(8))) short bf16x8;
typedef __attribute__((ext_vector_type(4))) float f32x4;

__device__ inline u16 f2bf(float f) {
    u32 u = __float_as_uint(f);
    u32 r = (u + 0x7fffu + ((u >> 16) & 1u)) >> 16;
    return (u16)r;
}

__device__ inline void load_lds16(const void* g, void* l) {
    __builtin_amdgcn_global_load_lds((__attribute__((address_space(1))) void*)g,
                                     (__attribute__((address_space(3))) void*)l,
                                     16, 0, 0);
}

// k1: per-row sumsq (fp32), bf16 conversion of total, per-block column partial sums.
__global__ __launch_bounds__(256) void k_prep(const float* __restrict__ src,
                                              const float* __restrict__ tgt,
                                              u16* __restrict__ Tb,
                                              float* __restrict__ sq,
                                              float* __restrict__ cp) {
    __shared__ float cs_l[4][DIM];
    const int b = blockIdx.x;
    const int tid = threadIdx.x;
    const int w = tid >> 6, lane = tid & 63;

    float cs[8];
#pragma unroll
    for (int e = 0; e < 8; ++e) cs[e] = 0.f;

#pragma unroll
    for (int j = 0; j < 4; ++j) {
        const int r = b * 16 + w * 4 + j;
        const float* rowp = (r < NS) ? (src + (size_t)r * DIM)
                                     : (tgt + (size_t)(r - NS) * DIM);
        float4 v0 = *(const float4*)(rowp + lane * 8);
        float4 v1 = *(const float4*)(rowp + lane * 8 + 4);
        float vx[8] = {v0.x, v0.y, v0.z, v0.w, v1.x, v1.y, v1.z, v1.w};
        float ss = 0.f;
#pragma unroll
        for (int e = 0; e < 8; ++e) { ss += vx[e] * vx[e]; cs[e] += vx[e]; }
        u32 pk[4];
#pragma unroll
        for (int e = 0; e < 4; ++e)
            pk[e] = (u32)f2bf(vx[2 * e]) | ((u32)f2bf(vx[2 * e + 1]) << 16);
        *(uint4*)(Tb + (size_t)r * DIM + lane * 8) = make_uint4(pk[0], pk[1], pk[2], pk[3]);
#pragma unroll
        for (int off = 32; off; off >>= 1) ss += __shfl_down(ss, off);
        if (lane == 0) sq[r] = ss;
    }
#pragma unroll
    for (int e = 0; e < 8; ++e) cs_l[w][lane * 8 + e] = cs[e];
    __syncthreads();
    float a0 = cs_l[0][tid] + cs_l[1][tid] + cs_l[2][tid] + cs_l[3][tid];
    float a1 = cs_l[0][tid + 256] + cs_l[1][tid + 256] + cs_l[2][tid + 256] + cs_l[3][tid + 256];
    cp[(size_t)b * DIM + tid] = a0;
    cp[(size_t)b * DIM + tid + 256] = a1;
}

// k2: bandwidth via sum(l2) = 2*N*sum(sq) - 2*||colsum||^2.
// MLP-friendly: each thread owns 2 columns, 4 independent accumulators, coalesced.
__global__ __launch_bounds__(256) void k_band(const float* __restrict__ sq,
                                              const float* __restrict__ cp,
                                              float* __restrict__ scales) {
    __shared__ double red[4];
    const int tid = threadIdx.x;
    const int w = tid >> 6, lane = tid & 63;

    double ssq = 0.0;
    for (int i = tid; i < NTOT; i += 256) ssq += (double)sq[i];

    double s2 = 0.0;
#pragma unroll
    for (int cc = 0; cc < 2; ++cc) {
        const int c = tid + cc * 256;
        float a0 = 0.f, a1 = 0.f, a2 = 0.f, a3 = 0.f;
#pragma unroll 8
        for (int b = 0; b < 512; b += 4) {
            a0 += cp[(size_t)(b + 0) * DIM + c];
            a1 += cp[(size_t)(b + 1) * DIM + c];
            a2 += cp[(size_t)(b + 2) * DIM + c];
            a3 += cp[(size_t)(b + 3) * DIM + c];
        }
        double sc = (double)a0 + (double)a1 + (double)a2 + (double)a3;
        s2 += sc * sc;
    }

    auto blkreduce = [&](double v) -> double {
#pragma unroll
        for (int off = 32; off; off >>= 1) v += __shfl_down(v, off);
        __syncthreads();
        if (lane == 0) red[w] = v;
        __syncthreads();
        return red[0] + red[1] + red[2] + red[3];
    };

    double sumsq = blkreduce(ssq);
    double s2t = blkreduce(s2);

    if (tid < 5) {
        const double nn = (double)NTOT;
        double bw = (2.0 * nn * sumsq - 2.0 * s2t) / (nn * nn - nn);
        const double fac[5] = {0.25, 0.5, 1.0, 2.0, 4.0};
        scales[tid] = (float)(-LOG2E / (bw * fac[tid] + 1e-8));
    }
}

// k3: symmetric main pass. Triangular grid (bi>=bj), 128x128 tile per block,
// fragment-major LDS staging (conflict-free ds_read_b128 at base+lane*16).
__global__ __launch_bounds__(256) void k_mmd(const u16* __restrict__ Tb,
                                             const float* __restrict__ sq,
                                             const float* __restrict__ scales,
                                             double* __restrict__ partials) {
    __shared__ __align__(16) u16 As[8 * 512];  // 8 fragments x 1 KiB (16 rows x 32 cols bf16)
    __shared__ __align__(16) u16 Bs[8 * 512];
    __shared__ double red[4];

    // integer triangular decomposition: t = bi*(bi+1)/2 + bj, bj<=bi
    const int t = blockIdx.x;
    int bi = (int)((sqrtf(8.0f * (float)t + 1.0f) - 1.0f) * 0.5f);
    // exact correction (handles any sqrtf rounding):
    while ((bi + 1) * (bi + 2) / 2 <= t) ++bi;
    while (bi * (bi + 1) / 2 > t) --bi;
    const int bj = t - bi * (bi + 1) / 2;

    const int tid = threadIdx.x;
    const int wid = tid >> 6, lane = tid & 63;
    const int wr = wid >> 1, wc = wid & 1;
    const int fr = lane & 15, fq = lane >> 4;

    f32x4 acc[4][4];
#pragma unroll
    for (int m = 0; m < 4; ++m)
#pragma unroll
        for (int n = 0; n < 4; ++n) acc[m][n] = (f32x4){0.f, 0.f, 0.f, 0.f};

    const int rowA0 = bi * 128, rowB0 = bj * 128;

    // Per-lane global source offsets: fragment f holds rows f*16+(lane&15),
    // k-octet (lane>>4)*8. LDS dest is linear lane*16B -> fragment-major.
    const size_t srcA0 = (size_t)(rowA0 + wid * 16 + fr) * DIM + fq * 8;
    const size_t srcA1 = (size_t)(rowA0 + (wid + 4) * 16 + fr) * DIM + fq * 8;
    const size_t srcB0 = (size_t)(rowB0 + wid * 16 + fr) * DIM + fq * 8;
    const size_t srcB1 = (size_t)(rowB0 + (wid + 4) * 16 + fr) * DIM + fq * 8;
    u16* ldsA0 = As + wid * 512;
    u16* ldsA1 = As + (wid + 4) * 512;
    u16* ldsB0 = Bs + wid * 512;
    u16* ldsB1 = Bs + (wid + 4) * 512;

    for (int kt = 0; kt < DIM / 32; ++kt) {
        const int k0 = kt * 32;
        load_lds16(Tb + srcA0 + k0, ldsA0);
        load_lds16(Tb + srcA1 + k0, ldsA1);
        load_lds16(Tb + srcB0 + k0, ldsB0);
        load_lds16(Tb + srcB1 + k0, ldsB1);
        __syncthreads();

        bf16x8 af[4], bf[4];
#pragma unroll
        for (int m = 0; m < 4; ++m)
            af[m] = *(const bf16x8*)(As + (wr * 4 + m) * 512 + lane * 8);
#pragma unroll
        for (int n = 0; n < 4; ++n)
            bf[n] = *(const bf16x8*)(Bs + (wc * 4 + n) * 512 + lane * 8);
#pragma unroll
        for (int m = 0; m < 4; ++m)
#pragma unroll
            for (int n = 0; n < 4; ++n)
                acc[m][n] = __builtin_amdgcn_mfma_f32_16x16x32_bf16(af[m], bf[n], acc[m][n], 0, 0, 0);
        __syncthreads();
    }

    // epilogue: l2 -> 5x exp2 -> f32 per-thread sum -> f64 reduce
    const float c0 = scales[0], c1 = scales[1], c2 = scales[2], c3 = scales[3], c4 = scales[4];
    float sqc[4];
#pragma unroll
    for (int n = 0; n < 4; ++n) sqc[n] = sq[rowB0 + wc * 64 + n * 16 + fr];

    float facc = 0.f;
#pragma unroll
    for (int m = 0; m < 4; ++m) {
        float4 s4 = *(const float4*)(sq + rowA0 + wr * 64 + m * 16 + fq * 4);
        float sqr[4] = {s4.x, s4.y, s4.z, s4.w};
#pragma unroll
        for (int n = 0; n < 4; ++n) {
#pragma unroll
            for (int r = 0; r < 4; ++r) {
                float g = acc[m][n][r];
                float l2 = fmaxf(sqr[r] + sqc[n] - 2.0f * g, 0.0f);
                facc += exp2f(c0 * l2) + exp2f(c1 * l2) + exp2f(c2 * l2)
                      + exp2f(c3 * l2) + exp2f(c4 * l2);
            }
        }
    }

    const double wfac = ((bi == bj) ? 1.0 : 2.0) *
                        (((bi < 32) == (bj < 32)) ? 1.0 : -1.0);
    double lacc = (double)facc;
#pragma unroll
    for (int off = 32; off; off >>= 1) lacc += __shfl_down(lacc, off);
    if (lane == 0) red[wid] = lacc;
    __syncthreads();
    if (tid == 0)
        partials[t] = (red[0] + red[1] + red[2] + red[3]) * wfac;
}

// k4: final reduce of 2080 block partials -> scalar
__global__ __launch_bounds__(256) void k_final(const double* __restrict__ partials,
                                               float* __restrict__ out) {
    __shared__ double red[4];
    const int tid = threadIdx.x;
    const int w = tid >> 6, lane = tid & 63;
    double v = 0.0;
    for (int i = tid; i < 2080; i += 256) v += partials[i];
#pragma unroll
    for (int off = 32; off; off >>= 1) v += __shfl_down(v, off);
    if (lane == 0) red[w] = v;
    __syncthreads();
    if (tid == 0)
        out[0] = (float)((red[0] + red[1] + red[2] + red[3]) / ((double)NS * (double)NS));
}

extern "C" void kernel_launch(void* const* d_in, const int* in_sizes, int n_in,
                              void* d_out, int out_size, void* d_ws, size_t ws_size,
                              hipStream_t stream) {
    const float* src = (const float*)d_in[0];
    const float* tgt = (const float*)d_in[1];
    char* ws = (char*)d_ws;

    u16* Tb       = (u16*)ws;                                                  // 8 MiB
    float* sq     = (float*)(ws + 8u * 1024 * 1024);                           // 32 KiB
    float* cp     = (float*)(ws + 8u * 1024 * 1024 + 32 * 1024);               // 1 MiB
    float* scales = (float*)(ws + 8u * 1024 * 1024 + 32 * 1024 + 1024 * 1024); // 32 B
    double* parts = (double*)(ws + 8u * 1024 * 1024 + 32 * 1024 + 1024 * 1024 + 256); // 17 KiB

    k_prep<<<512, 256, 0, stream>>>(src, tgt, Tb, sq, cp);
    k_band<<<1, 256, 0, stream>>>(sq, cp, scales);
    k_mmd<<<2080, 256, 0, stream>>>(Tb, sq, scales, parts);
    k_final<<<1, 256, 0, stream>>>(parts, (float*)d_out);
}

// Round 4
// 190.586 us; speedup vs baseline: 1.1915x; 1.0834x over previous
//
#include <hip/hip_runtime.h>
#include <stdint.h>

typedef uint16_t u16;
typedef uint32_t u32;

#define NS 4096
#define NTOT 8192
#define DIM 512
#define LOG2E 1.4426950408889634

typedef __attribute__((ext_vector_type(8))) short bf16x8;
typedef __attribute__((ext_vector_type(4))) float f32x4;

__device__ inline u16 f2bf(float f) {
    u32 u = __float_as_uint(f);
    u32 r = (u + 0x7fffu + ((u >> 16) & 1u)) >> 16;
    return (u16)r;
}

__device__ inline void load_lds16(const void* g, void* l) {
    __builtin_amdgcn_global_load_lds((__attribute__((address_space(1))) void*)g,
                                     (__attribute__((address_space(3))) void*)l,
                                     16, 0, 0);
}

// k1: per-row sumsq (fp32), bf16 conversion, colsum via f32 atomics.
__global__ __launch_bounds__(256) void k_prep(const float* __restrict__ src,
                                              const float* __restrict__ tgt,
                                              u16* __restrict__ Tb,
                                              float* __restrict__ sq,
                                              float* __restrict__ colsum) {
    __shared__ float cs_l[4][DIM];
    const int b = blockIdx.x;
    const int tid = threadIdx.x;
    const int w = tid >> 6, lane = tid & 63;

    float cs[8];
#pragma unroll
    for (int e = 0; e < 8; ++e) cs[e] = 0.f;

#pragma unroll
    for (int j = 0; j < 4; ++j) {
        const int r = b * 16 + w * 4 + j;
        const float* rowp = (r < NS) ? (src + (size_t)r * DIM)
                                     : (tgt + (size_t)(r - NS) * DIM);
        float4 v0 = *(const float4*)(rowp + lane * 8);
        float4 v1 = *(const float4*)(rowp + lane * 8 + 4);
        float vx[8] = {v0.x, v0.y, v0.z, v0.w, v1.x, v1.y, v1.z, v1.w};
        float ss = 0.f;
#pragma unroll
        for (int e = 0; e < 8; ++e) { ss += vx[e] * vx[e]; cs[e] += vx[e]; }
        u32 pk[4];
#pragma unroll
        for (int e = 0; e < 4; ++e)
            pk[e] = (u32)f2bf(vx[2 * e]) | ((u32)f2bf(vx[2 * e + 1]) << 16);
        *(uint4*)(Tb + (size_t)r * DIM + lane * 8) = make_uint4(pk[0], pk[1], pk[2], pk[3]);
#pragma unroll
        for (int off = 32; off; off >>= 1) ss += __shfl_down(ss, off);
        if (lane == 0) sq[r] = ss;
    }
#pragma unroll
    for (int e = 0; e < 8; ++e) cs_l[w][lane * 8 + e] = cs[e];
    __syncthreads();
    float a0 = cs_l[0][tid] + cs_l[1][tid] + cs_l[2][tid] + cs_l[3][tid];
    float a1 = cs_l[0][tid + 256] + cs_l[1][tid + 256] + cs_l[2][tid + 256] + cs_l[3][tid + 256];
    atomicAdd(&colsum[tid], a0);
    atomicAdd(&colsum[tid + 256], a1);
}

// k2: bandwidth via sum(l2) = 2*N*sum(sq) - 2*||colsum||^2. Tiny now (34 KB input).
__global__ __launch_bounds__(256) void k_band(const float* __restrict__ sq,
                                              const float* __restrict__ colsum,
                                              float* __restrict__ scales) {
    __shared__ double red[4];
    const int tid = threadIdx.x;
    const int w = tid >> 6, lane = tid & 63;

    double ssq = 0.0;
    for (int i = tid; i < NTOT; i += 256) ssq += (double)sq[i];

    double s2 = 0.0;
#pragma unroll
    for (int cc = 0; cc < 2; ++cc) {
        double v = (double)colsum[tid + cc * 256];
        s2 += v * v;
    }

    auto blkreduce = [&](double v) -> double {
#pragma unroll
        for (int off = 32; off; off >>= 1) v += __shfl_down(v, off);
        __syncthreads();
        if (lane == 0) red[w] = v;
        __syncthreads();
        return red[0] + red[1] + red[2] + red[3];
    };

    double sumsq = blkreduce(ssq);
    double s2t = blkreduce(s2);

    if (tid < 5) {
        const double nn = (double)NTOT;
        double bw = (2.0 * nn * sumsq - 2.0 * s2t) / (nn * nn - nn);
        const double fac[5] = {0.25, 0.5, 1.0, 2.0, 4.0};
        scales[tid] = (float)(-LOG2E / (bw * fac[tid] + 1e-8));
    }
}

// k3: symmetric main pass. XCD-swizzled triangular grid, 128x128 tile,
// fragment-major LDS, 2-phase double-buffered staging (T3 minimum recipe).
__global__ __launch_bounds__(256) void k_mmd(const u16* __restrict__ Tb,
                                             const float* __restrict__ sq,
                                             const float* __restrict__ scales,
                                             double* __restrict__ accum) {
    __shared__ __align__(16) u16 As[2][4096];  // 2 bufs x 8 frags x 1 KiB
    __shared__ __align__(16) u16 Bs[2][4096];
    __shared__ double red[4];

    // XCD-aware bijective swizzle (2080 = 8*260), then triangular decomposition.
    const int orig = blockIdx.x;
    const int t = (orig & 7) * 260 + (orig >> 3);
    int bi = (int)((sqrtf(8.0f * (float)t + 1.0f) - 1.0f) * 0.5f);
    while ((bi + 1) * (bi + 2) / 2 <= t) ++bi;
    while (bi * (bi + 1) / 2 > t) --bi;
    const int bj = t - bi * (bi + 1) / 2;

    const int tid = threadIdx.x;
    const int wid = tid >> 6, lane = tid & 63;
    const int wr = wid >> 1, wc = wid & 1;
    const int fr = lane & 15, fq = lane >> 4;

    f32x4 acc[4][4];
#pragma unroll
    for (int m = 0; m < 4; ++m)
#pragma unroll
        for (int n = 0; n < 4; ++n) acc[m][n] = (f32x4){0.f, 0.f, 0.f, 0.f};

    const int rowA0 = bi * 128, rowB0 = bj * 128;

    // Per-lane global source offsets (fragment-major: frag c = rows c*16+fr, octet fq).
    int offA[2], offB[2];
#pragma unroll
    for (int q = 0; q < 2; ++q) {
        offA[q] = (rowA0 + (wid * 2 + q) * 16 + fr) * DIM + fq * 8;
        offB[q] = (rowB0 + (wid * 2 + q) * 16 + fr) * DIM + fq * 8;
    }

    auto stage = [&](int buf, int k0) {
#pragma unroll
        for (int q = 0; q < 2; ++q) {
            load_lds16(Tb + offA[q] + k0, &As[buf][(wid * 2 + q) * 512]);
            load_lds16(Tb + offB[q] + k0, &Bs[buf][(wid * 2 + q) * 512]);
        }
    };

    auto compute = [&](int buf) {
        bf16x8 af[4], bf[4];
#pragma unroll
        for (int m = 0; m < 4; ++m)
            af[m] = *(const bf16x8*)(&As[buf][(wr * 4 + m) * 512] + lane * 8);
#pragma unroll
        for (int n = 0; n < 4; ++n)
            bf[n] = *(const bf16x8*)(&Bs[buf][(wc * 4 + n) * 512] + lane * 8);
#pragma unroll
        for (int m = 0; m < 4; ++m)
#pragma unroll
            for (int n = 0; n < 4; ++n)
                acc[m][n] = __builtin_amdgcn_mfma_f32_16x16x32_bf16(af[m], bf[n], acc[m][n], 0, 0, 0);
    };

    // 2-phase: stage(next) -> compute(cur) -> barrier (drains vmcnt for next iter).
    stage(0, 0);
    __syncthreads();
    for (int kt = 0; kt < 15; ++kt) {
        stage((kt & 1) ^ 1, (kt + 1) * 32);
        compute(kt & 1);
        __syncthreads();
    }
    compute(1);

    // epilogue: l2 -> 5x exp2 -> f32 per-thread sum -> f64 block reduce -> atomic.
    const float c0 = scales[0], c1 = scales[1], c2 = scales[2], c3 = scales[3], c4 = scales[4];
    float sqc[4];
#pragma unroll
    for (int n = 0; n < 4; ++n) sqc[n] = sq[rowB0 + wc * 64 + n * 16 + fr];

    float facc = 0.f;
#pragma unroll
    for (int m = 0; m < 4; ++m) {
        float4 s4 = *(const float4*)(sq + rowA0 + wr * 64 + m * 16 + fq * 4);
        float sqr[4] = {s4.x, s4.y, s4.z, s4.w};
#pragma unroll
        for (int n = 0; n < 4; ++n) {
#pragma unroll
            for (int r = 0; r < 4; ++r) {
                float g = acc[m][n][r];
                float l2 = fmaxf(sqr[r] + sqc[n] - 2.0f * g, 0.0f);
                facc += exp2f(c0 * l2) + exp2f(c1 * l2) + exp2f(c2 * l2)
                      + exp2f(c3 * l2) + exp2f(c4 * l2);
            }
        }
    }

    const double wfac = ((bi == bj) ? 1.0 : 2.0) *
                        (((bi < 32) == (bj < 32)) ? 1.0 : -1.0);
    double lacc = (double)facc;
#pragma unroll
    for (int off = 32; off; off >>= 1) lacc += __shfl_down(lacc, off);
    if (lane == 0) red[wid] = lacc;
    __syncthreads();
    if (tid == 0)
        atomicAdd(accum, (red[0] + red[1] + red[2] + red[3]) * wfac);
}

// k4: trivial final scale
__global__ void k_final(const double* __restrict__ accum, float* __restrict__ out) {
    if (threadIdx.x == 0)
        out[0] = (float)(accum[0] / ((double)NS * (double)NS));
}

extern "C" void kernel_launch(void* const* d_in, const int* in_sizes, int n_in,
                              void* d_out, int out_size, void* d_ws, size_t ws_size,
                              hipStream_t stream) {
    const float* src = (const float*)d_in[0];
    const float* tgt = (const float*)d_in[1];
    char* ws = (char*)d_ws;

    u16* Tb       = (u16*)ws;                                        // 8 MiB
    float* sq     = (float*)(ws + 8u * 1024 * 1024);                 // 32 KiB
    float* colsum = (float*)(ws + 8u * 1024 * 1024 + 32 * 1024);     // 2 KiB
    double* accum = (double*)(ws + 8u * 1024 * 1024 + 32 * 1024 + 2048); // 8 B
    float* scales = (float*)(ws + 8u * 1024 * 1024 + 36 * 1024);     // 32 B

    hipMemsetAsync(colsum, 0, 2048 + 8, stream);  // zero colsum + accum
    k_prep<<<512, 256, 0, stream>>>(src, tgt, Tb, sq, colsum);
    k_band<<<1, 256, 0, stream>>>(sq, colsum, scales);
    k_mmd<<<2080, 256, 0, stream>>>(Tb, sq, scales, accum);
    k_final<<<1, 64, 0, stream>>>(accum, (float*)d_out);
}

// Round 5
// 181.853 us; speedup vs baseline: 1.2487x; 1.0480x over previous
//
#include <hip/hip_runtime.h>
#include <stdint.h>

typedef uint16_t u16;
typedef uint32_t u32;

#define NS 4096
#define NTOT 8192
#define DIM 512

typedef __attribute__((ext_vector_type(8))) short bf16x8;
typedef __attribute__((ext_vector_type(4))) float f32x4;

__device__ inline u16 f2bf(float f) {
    u32 u = __float_as_uint(f);
    return (u16)((u + 0x7fffu + ((u >> 16) & 1u)) >> 16);
}

__device__ inline void load_lds16(const void* g, void* l) {
    __builtin_amdgcn_global_load_lds((__attribute__((address_space(1))) void*)g,
                                     (__attribute__((address_space(3))) void*)l,
                                     16, 0, 0);
}

// Fragment-major Tb layout: fragment (rb, kt) = 16 rows x 32 cols bf16 stored as a
// contiguous 1 KiB block at Tb + (rb*16+kt)*512 u16; interior order = lane-linear:
// u16 offset (fq*16+fr)*8 holds row rb*16+fr, k-octet fq. Staging then reads
// tile_base + lane*16B (coalesced) into linear LDS (global_load_lds requirement).

// k_prep: 128 blocks x 256 thr; block handles 64 rows. Fragment-major bf16 Tb,
// per-row sumsq, per-block colsum partials cp[128][512]. No atomics.
__global__ __launch_bounds__(256) void k_prep(const float* __restrict__ src,
                                              const float* __restrict__ tgt,
                                              u16* __restrict__ Tb,
                                              float* __restrict__ sq,
                                              float* __restrict__ cp) {
    __shared__ float cs_l[4][DIM];
    const int b = blockIdx.x, tid = threadIdx.x;
    const int w = tid >> 6, lane = tid & 63;
    const int kt = lane >> 2, fq = lane & 3;   // lane owns k-octet `lane` of each row

    float cs[8];
#pragma unroll
    for (int e = 0; e < 8; ++e) cs[e] = 0.f;

#pragma unroll
    for (int i = 0; i < 16; ++i) {
        const int r = b * 64 + w * 16 + i;
        const float* rowp = (r < NS) ? (src + (size_t)r * DIM)
                                     : (tgt + (size_t)(r - NS) * DIM);
        float4 v0 = *(const float4*)(rowp + lane * 8);
        float4 v1 = *(const float4*)(rowp + lane * 8 + 4);
        float vx[8] = {v0.x, v0.y, v0.z, v0.w, v1.x, v1.y, v1.z, v1.w};
        float ss = 0.f;
#pragma unroll
        for (int e = 0; e < 8; ++e) { ss += vx[e] * vx[e]; cs[e] += vx[e]; }
        u32 pk[4];
#pragma unroll
        for (int e = 0; e < 4; ++e)
            pk[e] = (u32)f2bf(vx[2 * e]) | ((u32)f2bf(vx[2 * e + 1]) << 16);
        const int rb = r >> 4, fr = r & 15;
        *(uint4*)(Tb + (size_t)(rb * 16 + kt) * 512 + (fq * 16 + fr) * 8) =
            make_uint4(pk[0], pk[1], pk[2], pk[3]);
#pragma unroll
        for (int off = 32; off; off >>= 1) ss += __shfl_down(ss, off);
        if (lane == 0) sq[r] = ss;
    }
#pragma unroll
    for (int e = 0; e < 8; ++e) cs_l[w][lane * 8 + e] = cs[e];
    __syncthreads();
    float a0 = cs_l[0][tid] + cs_l[1][tid] + cs_l[2][tid] + cs_l[3][tid];
    float a1 = cs_l[0][tid + 256] + cs_l[1][tid + 256] + cs_l[2][tid + 256] + cs_l[3][tid + 256];
    cp[(size_t)b * DIM + tid] = a0;
    cp[(size_t)b * DIM + tid + 256] = a1;
}

// k_band: bandwidth via sum(l2) = 2*N*sum(sq) - 2*||colsum||^2 (reads 288 KB).
// Also zeroes accum + counter for k_mmd. Natural-log scales: -1/(bw_i+eps).
__global__ __launch_bounds__(256) void k_band(const float* __restrict__ sq,
                                              const float* __restrict__ cp,
                                              float* __restrict__ scales,
                                              double* __restrict__ accum,
                                              u32* __restrict__ counter) {
    __shared__ double red[4];
    const int tid = threadIdx.x;
    const int w = tid >> 6, lane = tid & 63;

    double ssq = 0.0;
    for (int i = tid; i < NTOT; i += 256) ssq += (double)sq[i];

    double s2 = 0.0;
#pragma unroll
    for (int cc = 0; cc < 2; ++cc) {
        const int c = tid + cc * 256;
        float a0 = 0.f, a1 = 0.f, a2 = 0.f, a3 = 0.f;
#pragma unroll 8
        for (int b = 0; b < 128; b += 4) {
            a0 += cp[(size_t)(b + 0) * DIM + c];
            a1 += cp[(size_t)(b + 1) * DIM + c];
            a2 += cp[(size_t)(b + 2) * DIM + c];
            a3 += cp[(size_t)(b + 3) * DIM + c];
        }
        double sc = (double)a0 + (double)a1 + (double)a2 + (double)a3;
        s2 += sc * sc;
    }

    auto blkreduce = [&](double v) -> double {
#pragma unroll
        for (int off = 32; off; off >>= 1) v += __shfl_down(v, off);
        __syncthreads();
        if (lane == 0) red[w] = v;
        __syncthreads();
        return red[0] + red[1] + red[2] + red[3];
    };

    double sumsq = blkreduce(ssq);
    double s2t = blkreduce(s2);

    if (tid < 5) {
        const double nn = (double)NTOT;
        double bw = (2.0 * nn * sumsq - 2.0 * s2t) / (nn * nn - nn);
        const double fac[5] = {0.25, 0.5, 1.0, 2.0, 4.0};
        scales[tid] = (float)(-1.0 / (bw * fac[tid] + 1e-8));
    }
    if (tid == 5) *accum = 0.0;
    if (tid == 6) *counter = 0u;
}

// k_mmd: symmetric gram + kernel-sum. XCD-swizzled triangular grid, 128x128 tile,
// fragment-major contiguous staging, 2-phase dbuf, __expf epilogue, fused finish.
__global__ __launch_bounds__(256) void k_mmd(const u16* __restrict__ Tb,
                                             const float* __restrict__ sq,
                                             const float* __restrict__ scales,
                                             double* __restrict__ accum,
                                             u32* __restrict__ counter,
                                             float* __restrict__ out) {
    __shared__ __align__(16) u16 As[2][4096];
    __shared__ __align__(16) u16 Bs[2][4096];
    __shared__ double red[4];

    // XCD-aware bijective swizzle (2080 = 8*260), then triangular decomposition.
    const int orig = blockIdx.x;
    const int t = (orig & 7) * 260 + (orig >> 3);
    int bi = (int)((sqrtf(8.0f * (float)t + 1.0f) - 1.0f) * 0.5f);
    while ((bi + 1) * (bi + 2) / 2 <= t) ++bi;
    while (bi * (bi + 1) / 2 > t) --bi;
    const int bj = t - bi * (bi + 1) / 2;

    const int tid = threadIdx.x;
    const int wid = tid >> 6, lane = tid & 63;
    const int wr = wid >> 1, wc = wid & 1;
    const int fr = lane & 15, fq = lane >> 4;

    f32x4 acc[4][4];
#pragma unroll
    for (int m = 0; m < 4; ++m)
#pragma unroll
        for (int n = 0; n < 4; ++n) acc[m][n] = (f32x4){0.f, 0.f, 0.f, 0.f};

    const int rbA = bi * 8, rbB = bj * 8;   // 16-row fragment indices
    // Contiguous per-lane sources: frag (rb+c, kt) base + lane*16B.
    int offA[2], offB[2];
#pragma unroll
    for (int q = 0; q < 2; ++q) {
        offA[q] = (rbA + wid * 2 + q) * 16 * 512 + lane * 8;
        offB[q] = (rbB + wid * 2 + q) * 16 * 512 + lane * 8;
    }

    auto stage = [&](int buf, int kt) {
#pragma unroll
        for (int q = 0; q < 2; ++q) {
            load_lds16(Tb + offA[q] + kt * 512, &As[buf][(wid * 2 + q) * 512]);
            load_lds16(Tb + offB[q] + kt * 512, &Bs[buf][(wid * 2 + q) * 512]);
        }
    };

    auto compute = [&](int buf) {
        bf16x8 af[4], bf[4];
#pragma unroll
        for (int m = 0; m < 4; ++m)
            af[m] = *(const bf16x8*)(&As[buf][(wr * 4 + m) * 512] + lane * 8);
#pragma unroll
        for (int n = 0; n < 4; ++n)
            bf[n] = *(const bf16x8*)(&Bs[buf][(wc * 4 + n) * 512] + lane * 8);
#pragma unroll
        for (int m = 0; m < 4; ++m)
#pragma unroll
            for (int n = 0; n < 4; ++n)
                acc[m][n] = __builtin_amdgcn_mfma_f32_16x16x32_bf16(af[m], bf[n], acc[m][n], 0, 0, 0);
    };

    stage(0, 0);
    __syncthreads();
    for (int kt = 0; kt < 15; ++kt) {
        stage((kt & 1) ^ 1, kt + 1);
        compute(kt & 1);
        __syncthreads();
    }
    compute(1);

    // epilogue: l2 -> 5x __expf -> f32 per-thread sum -> f64 block reduce.
    const float c0 = scales[0], c1 = scales[1], c2 = scales[2], c3 = scales[3], c4 = scales[4];
    const int rowA0 = bi * 128, rowB0 = bj * 128;
    float sqc[4];
#pragma unroll
    for (int n = 0; n < 4; ++n) sqc[n] = sq[rowB0 + wc * 64 + n * 16 + fr];

    float facc = 0.f;
#pragma unroll
    for (int m = 0; m < 4; ++m) {
        float4 s4 = *(const float4*)(sq + rowA0 + wr * 64 + m * 16 + fq * 4);
        float sqr[4] = {s4.x, s4.y, s4.z, s4.w};
#pragma unroll
        for (int n = 0; n < 4; ++n) {
#pragma unroll
            for (int r = 0; r < 4; ++r) {
                float g = acc[m][n][r];
                float l2 = fmaxf(sqr[r] + sqc[n] - 2.0f * g, 0.0f);
                facc += __expf(c0 * l2) + __expf(c1 * l2) + __expf(c2 * l2)
                      + __expf(c3 * l2) + __expf(c4 * l2);
            }
        }
    }

    const double wfac = ((bi == bj) ? 1.0 : 2.0) *
                        (((bi < 32) == (bj < 32)) ? 1.0 : -1.0);
    double lacc = (double)facc;
#pragma unroll
    for (int off = 32; off; off >>= 1) lacc += __shfl_down(lacc, off);
    if (lane == 0) red[wid] = lacc;
    __syncthreads();

    if (tid == 0) {
        atomicAdd(accum, (red[0] + red[1] + red[2] + red[3]) * wfac);
        __threadfence();
        u32 done = atomicAdd(counter, 1u);
        if (done == 2079u) {
            double tot = atomicAdd(accum, 0.0);   // device-scope coherent read
            out[0] = (float)(tot / ((double)NS * (double)NS));
        }
    }
}

extern "C" void kernel_launch(void* const* d_in, const int* in_sizes, int n_in,
                              void* d_out, int out_size, void* d_ws, size_t ws_size,
                              hipStream_t stream) {
    const float* src = (const float*)d_in[0];
    const float* tgt = (const float*)d_in[1];
    char* ws = (char*)d_ws;

    const size_t MB8 = 8u * 1024 * 1024;
    u16* Tb       = (u16*)ws;                                // 8 MiB fragment-major
    float* sq     = (float*)(ws + MB8);                      // 32 KiB
    float* cp     = (float*)(ws + MB8 + 32 * 1024);          // 256 KiB
    float* scales = (float*)(ws + MB8 + 288 * 1024);         // 32 B
    double* accum = (double*)(ws + MB8 + 288 * 1024 + 64);   // 8 B
    u32* counter  = (u32*)(ws + MB8 + 288 * 1024 + 80);      // 4 B

    k_prep<<<128, 256, 0, stream>>>(src, tgt, Tb, sq, cp);
    k_band<<<1, 256, 0, stream>>>(sq, cp, scales, accum, counter);
    k_mmd<<<2080, 256, 0, stream>>>(Tb, sq, scales, accum, counter, (float*)d_out);
}